// Round 3
// baseline (503.196 us; speedup 1.0000x reference)
//
#include <hip/hip_runtime.h>
#include <math.h>

#define BB 8
#define CCH 256
#define LLEN 4096
#define L1V 4094
#define L2V 4092
#define L3V 4088
#define NCOL (BB * L2V)   // 32736
#define PIT 260           // staging pitch for [pos][ch] tiles in fused conv

// ---------- prep: transpose attention weights into ws ----------
__global__ void prep_kernel(const float* __restrict__ wa1, const float* __restrict__ wa2,
                            float* __restrict__ wt1T, float* __restrict__ wt2T) {
    int i = blockIdx.x;
    int o = threadIdx.x;
    if (i < 64) {
        wt1T[i * 256 + o] = wa1[o * 64 + i];
    } else {
        int ii = i - 64;
        if (ii < 32) wt2T[ii * 256 + o] = wa2[o * 32 + ii];
    }
}

// ---------- K1: fused conv1(k=3)+shuffle+conv2(k=3)+shuffle : x -> t2 [B,L2,C] ----------
__global__ __launch_bounds__(256, 4) void conv12_kernel(const float* __restrict__ x,
                                                        const float* __restrict__ w1,
                                                        const float* __restrict__ b1,
                                                        const float* __restrict__ w2,
                                                        const float* __restrict__ b2,
                                                        float* __restrict__ t2) {
    // One buffer, three lives:
    //  (a) x tile   [256ch][36pos] pitch 36 + (ch>>5)*4 skew   (max 9243)
    //  (b) h1 tile  [34pos][256ch] pitch 260                   (max 8835)
    //  (c) out tile [32pos][256ch] pitch 260                   (max 8315)
    __shared__ float xs[9248];
    const int b = blockIdx.y;
    const int l0 = blockIdx.x * 32;
    const int t = threadIdx.x;

    // ---- stage x tile ----
#pragma unroll
    for (int j = 0; j < 9; ++j) {
        int f = t + 256 * j;           // 0..2303 = 256 rows * 9 float4
        int row = f / 9;
        int q = f - row * 9;
        size_t rb = (size_t)(b * CCH + row) * LLEN;
        int base = l0 + 4 * q;
        float4 v;
        if (base + 3 < LLEN) {
            v = *(const float4*)(x + rb + base);
        } else {
            v.x = x[rb + min(base + 0, LLEN - 1)];
            v.y = x[rb + min(base + 1, LLEN - 1)];
            v.z = x[rb + min(base + 2, LLEN - 1)];
            v.w = x[rb + min(base + 3, LLEN - 1)];
        }
        *(float4*)&xs[row * 36 + (row >> 5) * 4 + 4 * q] = v;
    }
    __syncthreads();

    const int oc = t;
    const int go = oc >> 5;
    const int nc = (oc & 31) * 8 + (oc >> 5);   // channel-shuffle scatter

    // ---- conv1: 34 output positions, weights prefetched as float4 chunks ----
    float acc1[34];
#pragma unroll
    for (int l = 0; l < 34; ++l) acc1[l] = 0.f;
    {
        const float4* wrow = (const float4*)(w1 + oc * 96);
        float4 wc0 = wrow[0], wc1 = wrow[1], wc2 = wrow[2];
        for (int ch = 0; ch < 8; ++ch) {
            float4 wn0 = wrow[min(3 * ch + 3, 23)];
            float4 wn1 = wrow[min(3 * ch + 4, 23)];
            float4 wn2 = wrow[min(3 * ch + 5, 23)];
            float wf[12];
            *(float4*)&wf[0] = wc0; *(float4*)&wf[4] = wc1; *(float4*)&wf[8] = wc2;
#pragma unroll
            for (int ii = 0; ii < 4; ++ii) {
                int row = go * 32 + ch * 4 + ii;
                int base = row * 36 + go * 4;
                float w0 = wf[ii * 3 + 0], w1v = wf[ii * 3 + 1], w2v = wf[ii * 3 + 2];
#pragma unroll
                for (int q = 0; q < 9; ++q) {
                    float4 v = *(const float4*)&xs[base + 4 * q];
#pragma unroll
                    for (int jj = 0; jj < 4; ++jj) {
                        int e = 4 * q + jj;
                        float xv = (&v.x)[jj];
                        if (e < 34) acc1[e] += w0 * xv;
                        if (e >= 1 && e <= 34) acc1[e - 1] += w1v * xv;
                        if (e >= 2 && e <= 35) acc1[e - 2] += w2v * xv;
                    }
                }
            }
            wc0 = wn0; wc1 = wn1; wc2 = wn2;
        }
    }
    float bias1 = b1[oc];
    __syncthreads();

    // ---- stage h1 (shuffled channels) ----
#pragma unroll
    for (int l = 0; l < 34; ++l) xs[l * PIT + nc] = acc1[l] + bias1;
    __syncthreads();

    // ---- conv2: 32 outputs from 34 h1 positions ----
    float acc2[32];
#pragma unroll
    for (int l = 0; l < 32; ++l) acc2[l] = 0.f;
    {
        const float4* wrow = (const float4*)(w2 + oc * 96);
        float4 wc0 = wrow[0], wc1 = wrow[1], wc2 = wrow[2];
        for (int i4 = 0; i4 < 8; ++i4) {
            float4 wn0 = wrow[min(3 * i4 + 3, 23)];
            float4 wn1 = wrow[min(3 * i4 + 4, 23)];
            float4 wn2 = wrow[min(3 * i4 + 5, 23)];
            float wf[12];
            *(float4*)&wf[0] = wc0; *(float4*)&wf[4] = wc1; *(float4*)&wf[8] = wc2;
            int colbase = go * 32 + i4 * 4;
#pragma unroll
            for (int p = 0; p < 34; ++p) {
                float4 rv = *(const float4*)&xs[p * PIT + colbase];
#pragma unroll
                for (int cc = 0; cc < 4; ++cc) {
                    float xv = (&rv.x)[cc];
#pragma unroll
                    for (int k = 0; k < 3; ++k) {
                        int l = p - k;
                        if (l >= 0 && l < 32) acc2[l] += wf[cc * 3 + k] * xv;
                    }
                }
            }
            wc0 = wn0; wc1 = wn1; wc2 = wn2;
        }
    }
    float bias2 = b2[oc];
    __syncthreads();

    // ---- stage conv2 output (shuffled channels) ----
#pragma unroll
    for (int l = 0; l < 32; ++l) xs[l * PIT + nc] = acc2[l] + bias2;
    __syncthreads();

    // ---- coalesced float4 store to t2 ----
#pragma unroll
    for (int j = 0; j < 8; ++j) {
        int idx = t + 256 * j;          // 2048 granules = 32 rows * 64
        int row = idx >> 6;
        int c4 = (idx & 63) * 4;
        if (l0 + row < L2V) {
            float4 v = *(const float4*)&xs[row * PIT + c4];
            *(float4*)(t2 + (size_t)(b * L2V + l0 + row) * CCH + c4) = v;
        }
    }
}

// ---------- K3: per-column sort + attention gate, in-place on t2 (unchanged) ----------
__device__ __forceinline__ void ce_pair(float& a, float& b, bool up) {
    float lo = fminf(a, b), hi = fmaxf(a, b);
    a = up ? lo : hi;
    b = up ? hi : lo;
}

__device__ __forceinline__ void bitonic256(float v[4], int lane) {
#pragma unroll
    for (int k = 2; k <= 256; k <<= 1) {
#pragma unroll
        for (int j = k >> 1; j > 0; j >>= 1) {
            if (j >= 4) {
                int lm = j >> 2;
                bool upper = (lane & lm) != 0;
#pragma unroll
                for (int r = 0; r < 4; ++r) {
                    float other = __shfl_xor(v[r], lm, 64);
                    bool dirUp = (((4 * lane + r) & k) == 0);
                    bool keepMin = (dirUp != upper);
                    float lo = fminf(v[r], other), hi = fmaxf(v[r], other);
                    v[r] = keepMin ? lo : hi;
                }
            } else if (j == 2) {
#pragma unroll
                for (int r = 0; r < 2; ++r) {
                    bool up = (((4 * lane + r) & k) == 0);
                    ce_pair(v[r], v[r + 2], up);
                }
            } else {
#pragma unroll
                for (int r = 0; r < 4; r += 2) {
                    bool up = (((4 * lane + r) & k) == 0);
                    ce_pair(v[r], v[r + 1], up);
                }
            }
        }
    }
}

__global__ __launch_bounds__(256, 4) void attn_kernel(float* __restrict__ t2,
                                                      const float* __restrict__ wt1T,
                                                      const float* __restrict__ wt2T,
                                                      const float* __restrict__ ba1,
                                                      const float* __restrict__ ba2) {
    __shared__ float sm[8320];           // 4 waves * 2080 floats
    const int t = threadIdx.x;
    const int wv = t >> 6;
    const int lane = t & 63;
    const int wbase = wv * 2080;
    const int go = lane >> 3;

    float4 ba1v = *(const float4*)&ba1[4 * lane];
    float4 ba2v = *(const float4*)&ba2[4 * lane];

    const int colBase = blockIdx.x * 16 + wv * 4;

    float4 hv[4];
#pragma unroll
    for (int cc = 0; cc < 4; ++cc) {
        hv[cc] = *(const float4*)(t2 + (size_t)(colBase + cc) * CCH + 4 * lane);
    }
#pragma unroll
    for (int r = 0; r < 4; ++r) {
        int e = 4 * lane + r;
        int slot = ((e >> 6) + 4) * 65 + (e & 63);
        float4 vvv = make_float4((&hv[0].x)[r], (&hv[1].x)[r], (&hv[2].x)[r], (&hv[3].x)[r]);
        *(float4*)&sm[wbase + slot * 4] = vvv;
    }
    float srt[4][4];
#pragma unroll
    for (int cc = 0; cc < 4; ++cc) {
        float s[4] = {hv[cc].x, hv[cc].y, hv[cc].z, hv[cc].w};
        bitonic256(s, lane);
        srt[cc][0] = s[0]; srt[cc][1] = s[1]; srt[cc][2] = s[2]; srt[cc][3] = s[3];
    }
#pragma unroll
    for (int r = 0; r < 4; ++r) {
        int e = 4 * lane + r;
        int slot = (e >> 6) * 65 + (e & 63);
        float4 vvv = make_float4(srt[0][r], srt[1][r], srt[2][r], srt[3][r]);
        *(float4*)&sm[wbase + slot * 4] = vvv;
    }

    float4 acc[4];
#pragma unroll
    for (int cc = 0; cc < 4; ++cc) acc[cc] = make_float4(0.f, 0.f, 0.f, 0.f);
#pragma unroll 4
    for (int i = 0; i < 64; ++i) {
        float4 w4 = *(const float4*)&wt1T[i * 256 + 4 * lane];
        float4 cv = *(const float4*)&sm[wbase + (go * 65 + i) * 4];
#pragma unroll
        for (int cc = 0; cc < 4; ++cc) {
            float cvv = (&cv.x)[cc];
            acc[cc].x += w4.x * cvv;
            acc[cc].y += w4.y * cvv;
            acc[cc].z += w4.z * cvv;
            acc[cc].w += w4.w * cvv;
        }
    }
#pragma unroll
    for (int r = 0; r < 4; ++r) {
        float bb = (&ba1v.x)[r];
        float4 vvv = make_float4((&acc[0].x)[r] + bb, (&acc[1].x)[r] + bb,
                                 (&acc[2].x)[r] + bb, (&acc[3].x)[r] + bb);
        *(float4*)&sm[wbase + (5 * lane + r) * 4] = vvv;
    }

    float4 acc2[4];
#pragma unroll
    for (int cc = 0; cc < 4; ++cc) acc2[cc] = make_float4(0.f, 0.f, 0.f, 0.f);
#pragma unroll 4
    for (int i = 0; i < 32; ++i) {
        float4 w4 = *(const float4*)&wt2T[i * 256 + 4 * lane];
        int idx = ((i & 7) << 5) + (go << 2) + (i >> 3);
        int slotA = idx + (idx >> 2);
        float4 av = *(const float4*)&sm[wbase + slotA * 4];
#pragma unroll
        for (int cc = 0; cc < 4; ++cc) {
            float avv = (&av.x)[cc];
            acc2[cc].x += w4.x * avv;
            acc2[cc].y += w4.y * avv;
            acc2[cc].z += w4.z * avv;
            acc2[cc].w += w4.w * avv;
        }
    }
#pragma unroll
    for (int cc = 0; cc < 4; ++cc) {
        float zx = acc2[cc].x + ba2v.x;
        float zy = acc2[cc].y + ba2v.y;
        float zz = acc2[cc].z + ba2v.z;
        float zw = acc2[cc].w + ba2v.w;
        float4 res;
        res.x = hv[cc].x * (1.f / (1.f + __expf(-zx)));
        res.y = hv[cc].y * (1.f / (1.f + __expf(-zy)));
        res.z = hv[cc].z * (1.f / (1.f + __expf(-zz)));
        res.w = hv[cc].w * (1.f / (1.f + __expf(-zw)));
        *(float4*)(t2 + (size_t)(colBase + cc) * CCH + 4 * lane) = res;
    }
}

// ---------- K4: grouped conv k=5 over t2 [B,L2,C] -> out [B,C,L3] ----------
__global__ __launch_bounds__(256, 4) void conv3_kernel(const float* __restrict__ hm,
                                                       const float* __restrict__ w3,
                                                       const float* __restrict__ b3,
                                                       float* __restrict__ out) {
    __shared__ float ts[10368];  // [36][288], skewed
    const int b = blockIdx.y;
    const int l0 = blockIdx.x * 32;
    const int t = threadIdx.x;

#pragma unroll
    for (int j = 0; j < 9; ++j) {
        int f = t + 256 * j;            // 2304 = 36*64
        int p = f >> 6;
        int c4 = (f & 63) * 4;
        int row = min(l0 + p, L2V - 1);
        float4 v = *(const float4*)(hm + (size_t)(b * L2V + row) * CCH + c4);
        *(float4*)&ts[p * 288 + (c4 >> 5) * 36 + (c4 & 31)] = v;
    }
    __syncthreads();

    const int oc = t;
    const int go = t >> 5;
    float acc[32];
#pragma unroll
    for (int l = 0; l < 32; ++l) acc[l] = 0.f;

    {
        const float4* wrow = (const float4*)(w3 + oc * 160);
        float4 wc0 = wrow[0], wc1 = wrow[1], wc2 = wrow[2], wc3 = wrow[3], wc4 = wrow[4];
        for (int i4 = 0; i4 < 8; ++i4) {
            float4 wn0 = wrow[min(5 * i4 + 5, 39)];
            float4 wn1 = wrow[min(5 * i4 + 6, 39)];
            float4 wn2 = wrow[min(5 * i4 + 7, 39)];
            float4 wn3 = wrow[min(5 * i4 + 8, 39)];
            float4 wn4 = wrow[min(5 * i4 + 9, 39)];
            float wf[20];
            *(float4*)&wf[0] = wc0; *(float4*)&wf[4] = wc1; *(float4*)&wf[8] = wc2;
            *(float4*)&wf[12] = wc3; *(float4*)&wf[16] = wc4;
            int colbase = go * 36 + i4 * 4;
#pragma unroll
            for (int p = 0; p < 36; ++p) {
                float4 rv = *(const float4*)&ts[p * 288 + colbase];
#pragma unroll
                for (int cc = 0; cc < 4; ++cc) {
                    float xv = (&rv.x)[cc];
#pragma unroll
                    for (int k = 0; k < 5; ++k) {
                        int l = p - k;
                        if (l >= 0 && l < 32) acc[l] += wf[cc * 5 + k] * xv;
                    }
                }
            }
            wc0 = wn0; wc1 = wn1; wc2 = wn2; wc3 = wn3; wc4 = wn4;
        }
    }
    float bias = b3[oc];
    float* dst = out + (size_t)(b * CCH + oc) * L3V + l0;
#pragma unroll
    for (int l4 = 0; l4 < 8; ++l4) {
        int gl = l0 + 4 * l4;
        if (gl + 3 < L3V) {
            float4 v;
            v.x = acc[4 * l4 + 0] + bias;
            v.y = acc[4 * l4 + 1] + bias;
            v.z = acc[4 * l4 + 2] + bias;
            v.w = acc[4 * l4 + 3] + bias;
            *(float4*)(dst + 4 * l4) = v;
        } else {
#pragma unroll
            for (int c = 0; c < 4; ++c) {
                if (gl + c < L3V) dst[4 * l4 + c] = acc[4 * l4 + c] + bias;
            }
        }
    }
}

extern "C" void kernel_launch(void* const* d_in, const int* in_sizes, int n_in,
                              void* d_out, int out_size, void* d_ws, size_t ws_size,
                              hipStream_t stream) {
    const float* x   = (const float*)d_in[0];
    const float* w1  = (const float*)d_in[1];
    const float* b1  = (const float*)d_in[2];
    const float* w2  = (const float*)d_in[3];
    const float* b2  = (const float*)d_in[4];
    const float* wa1 = (const float*)d_in[5];
    const float* ba1 = (const float*)d_in[6];
    const float* wa2 = (const float*)d_in[7];
    const float* ba2 = (const float*)d_in[8];
    const float* w3  = (const float*)d_in[9];
    const float* b3  = (const float*)d_in[10];
    float* out = (float*)d_out;

    char* ws = (char*)d_ws;
    float* t2   = (float*)ws;                                   // 8*4092*256 f32 = 33.5 MB
    float* wt1T = (float*)(ws + ((size_t)48 << 20));            // 64*256 f32
    float* wt2T = wt1T + 64 * 256;                              // 32*256 f32

    hipLaunchKernelGGL(prep_kernel, dim3(96), dim3(256), 0, stream, wa1, wa2, wt1T, wt2T);
    hipLaunchKernelGGL(conv12_kernel, dim3(128, BB), dim3(256), 0, stream, x, w1, b1, w2, b2, t2);
    hipLaunchKernelGGL(attn_kernel, dim3(2046), dim3(256), 0, stream, t2, wt1T, wt2T, ba1, ba2);
    hipLaunchKernelGGL(conv3_kernel, dim3(128, BB), dim3(256), 0, stream, t2, w3, b3, out);
}

// Round 4
// 494.580 us; speedup vs baseline: 1.0174x; 1.0174x over previous
//
#include <hip/hip_runtime.h>
#include <math.h>

#define BB 8
#define CCH 256
#define LLEN 4096
#define L1V 4094
#define L2V 4092
#define L3V 4088
#define NCOL (BB * L2V)   // 32736

// constant-index float4 component extraction (folds at compile time; no address-of)
#define F4C(v, j) ((j) == 0 ? (v).x : ((j) == 1 ? (v).y : ((j) == 2 ? (v).z : (v).w)))
#define TAP12(a, b, c, f) ((f) < 4 ? F4C(a, (f)) : ((f) < 8 ? F4C(b, (f) - 4) : F4C(c, (f) - 8)))
#define TAP20(a, b, c, d, e, f) \
    ((f) < 4 ? F4C(a, (f)) : ((f) < 8 ? F4C(b, (f) - 4) : ((f) < 12 ? F4C(c, (f) - 8) : \
     ((f) < 16 ? F4C(d, (f) - 12) : F4C(e, (f) - 16)))))

// ---------- prep: transpose attention weights into ws ----------
__global__ void prep_kernel(const float* __restrict__ wa1, const float* __restrict__ wa2,
                            float* __restrict__ wt1T, float* __restrict__ wt2T) {
    int i = blockIdx.x;
    int o = threadIdx.x;
    if (i < 64) {
        wt1T[i * 256 + o] = wa1[o * 64 + i];
    } else {
        int ii = i - 64;
        if (ii < 32) wt2T[ii * 256 + o] = wa2[o * 32 + ii];
    }
}

// ---------- K1: fused conv1(k=3)+shuffle+conv2(k=3)+shuffle : x -> t2 [B,L2,C] ----------
// 16 output positions per block. Registers: acc1[18] then acc2[16] (+3 weight f4s live).
__global__ __launch_bounds__(256, 6) void conv12_kernel(const float* __restrict__ x,
                                                        const float* __restrict__ w1,
                                                        const float* __restrict__ b1,
                                                        const float* __restrict__ w2,
                                                        const float* __restrict__ b2,
                                                        float* __restrict__ t2) {
    // buffer lives: (a) x tile [256ch][20pos] contiguous (5120 floats)
    //               (b) h1 tile [18pos][260] (<=4676) (c) out tile [16pos][260]
    __shared__ float xs[5120];
    const int b = blockIdx.y;
    const int l0 = blockIdx.x * 16;
    const int t = threadIdx.x;

    // ---- stage x tile: 1280 float4 granules, LDS addr = 4*f (conflict-free) ----
#pragma unroll
    for (int j = 0; j < 5; ++j) {
        int f = t + 256 * j;            // 0..1279
        int row = f / 5;
        int q = f - row * 5;
        size_t rb = (size_t)(b * CCH + row) * LLEN;
        int base = l0 + 4 * q;
        float4 v;
        if (base + 3 < LLEN) {
            v = *(const float4*)(x + rb + base);
        } else {
            v.x = x[rb + min(base + 0, LLEN - 1)];
            v.y = x[rb + min(base + 1, LLEN - 1)];
            v.z = x[rb + min(base + 2, LLEN - 1)];
            v.w = x[rb + min(base + 3, LLEN - 1)];
        }
        *(float4*)&xs[4 * f] = v;
    }
    __syncthreads();

    const int oc = t;
    const int go = oc >> 5;
    const int nc = (oc & 31) * 8 + go;   // channel-shuffle scatter

    // ---- conv1: 18 h1 positions from 20 x elems ----
    float acc1[18];
#pragma unroll
    for (int l = 0; l < 18; ++l) acc1[l] = 0.f;
    {
        const float4* w1r = (const float4*)(w1 + oc * 96);
#pragma unroll 1
        for (int c4 = 0; c4 < 8; ++c4) {
            float4 wa = w1r[3 * c4 + 0];
            float4 wb = w1r[3 * c4 + 1];
            float4 wc = w1r[3 * c4 + 2];
#pragma unroll
            for (int ii = 0; ii < 4; ++ii) {
                const float* xrow = &xs[(go * 32 + c4 * 4 + ii) * 20];
#pragma unroll
                for (int q = 0; q < 5; ++q) {
                    float4 v = *(const float4*)(xrow + 4 * q);
#pragma unroll
                    for (int jj = 0; jj < 4; ++jj) {
                        const int e = 4 * q + jj;
                        float xv = F4C(v, jj);
                        if (e < 18)           acc1[e]     += TAP12(wa, wb, wc, ii * 3 + 0) * xv;
                        if (e >= 1 && e <= 18) acc1[e - 1] += TAP12(wa, wb, wc, ii * 3 + 1) * xv;
                        if (e >= 2 && e <= 19) acc1[e - 2] += TAP12(wa, wb, wc, ii * 3 + 2) * xv;
                    }
                }
            }
        }
    }
    float bias1 = b1[oc];
    __syncthreads();

    // ---- stage h1 (shuffled channels), pitch 260 ----
#pragma unroll
    for (int l = 0; l < 18; ++l) xs[l * 260 + nc] = acc1[l] + bias1;
    __syncthreads();

    // ---- conv2: 16 outputs from 18 h1 positions ----
    float acc2[16];
#pragma unroll
    for (int l = 0; l < 16; ++l) acc2[l] = 0.f;
    {
        const float4* w2r = (const float4*)(w2 + oc * 96);
#pragma unroll 1
        for (int i4 = 0; i4 < 8; ++i4) {
            float4 wa = w2r[3 * i4 + 0];
            float4 wb = w2r[3 * i4 + 1];
            float4 wc = w2r[3 * i4 + 2];
            const int colbase = go * 32 + i4 * 4;
#pragma unroll
            for (int p = 0; p < 18; ++p) {
                float4 rv = *(const float4*)&xs[p * 260 + colbase];
#pragma unroll
                for (int cc = 0; cc < 4; ++cc) {
                    float xv = F4C(rv, cc);
#pragma unroll
                    for (int k = 0; k < 3; ++k) {
                        const int l = p - k;
                        if (l >= 0 && l < 16) acc2[l] += TAP12(wa, wb, wc, cc * 3 + k) * xv;
                    }
                }
            }
        }
    }
    float bias2 = b2[oc];
    __syncthreads();

    // ---- stage conv2 output (shuffled channels) ----
#pragma unroll
    for (int l = 0; l < 16; ++l) xs[l * 260 + nc] = acc2[l] + bias2;
    __syncthreads();

    // ---- coalesced float4 store to t2 ----
#pragma unroll
    for (int j = 0; j < 4; ++j) {
        int idx = t + 256 * j;          // 1024 granules = 16 rows * 64
        int row = idx >> 6;
        int c4 = (idx & 63) * 4;
        if (l0 + row < L2V) {
            float4 v = *(const float4*)&xs[row * 260 + c4];
            *(float4*)(t2 + (size_t)(b * L2V + l0 + row) * CCH + c4) = v;
        }
    }
}

// ---------- K3: per-column sort + attention gate, in-place on t2 (unchanged) ----------
__device__ __forceinline__ void ce_pair(float& a, float& b, bool up) {
    float lo = fminf(a, b), hi = fmaxf(a, b);
    a = up ? lo : hi;
    b = up ? hi : lo;
}

__device__ __forceinline__ void bitonic256(float v[4], int lane) {
#pragma unroll
    for (int k = 2; k <= 256; k <<= 1) {
#pragma unroll
        for (int j = k >> 1; j > 0; j >>= 1) {
            if (j >= 4) {
                int lm = j >> 2;
                bool upper = (lane & lm) != 0;
#pragma unroll
                for (int r = 0; r < 4; ++r) {
                    float other = __shfl_xor(v[r], lm, 64);
                    bool dirUp = (((4 * lane + r) & k) == 0);
                    bool keepMin = (dirUp != upper);
                    float lo = fminf(v[r], other), hi = fmaxf(v[r], other);
                    v[r] = keepMin ? lo : hi;
                }
            } else if (j == 2) {
#pragma unroll
                for (int r = 0; r < 2; ++r) {
                    bool up = (((4 * lane + r) & k) == 0);
                    ce_pair(v[r], v[r + 2], up);
                }
            } else {
#pragma unroll
                for (int r = 0; r < 4; r += 2) {
                    bool up = (((4 * lane + r) & k) == 0);
                    ce_pair(v[r], v[r + 1], up);
                }
            }
        }
    }
}

__global__ __launch_bounds__(256, 4) void attn_kernel(float* __restrict__ t2,
                                                      const float* __restrict__ wt1T,
                                                      const float* __restrict__ wt2T,
                                                      const float* __restrict__ ba1,
                                                      const float* __restrict__ ba2) {
    __shared__ float sm[8320];           // 4 waves * 2080 floats
    const int t = threadIdx.x;
    const int wv = t >> 6;
    const int lane = t & 63;
    const int wbase = wv * 2080;
    const int go = lane >> 3;

    float4 ba1v = *(const float4*)&ba1[4 * lane];
    float4 ba2v = *(const float4*)&ba2[4 * lane];

    const int colBase = blockIdx.x * 16 + wv * 4;

    float4 hv[4];
#pragma unroll
    for (int cc = 0; cc < 4; ++cc) {
        hv[cc] = *(const float4*)(t2 + (size_t)(colBase + cc) * CCH + 4 * lane);
    }
#pragma unroll
    for (int r = 0; r < 4; ++r) {
        int e = 4 * lane + r;
        int slot = ((e >> 6) + 4) * 65 + (e & 63);
        float4 vvv = make_float4((&hv[0].x)[r], (&hv[1].x)[r], (&hv[2].x)[r], (&hv[3].x)[r]);
        *(float4*)&sm[wbase + slot * 4] = vvv;
    }
    float srt[4][4];
#pragma unroll
    for (int cc = 0; cc < 4; ++cc) {
        float s[4] = {hv[cc].x, hv[cc].y, hv[cc].z, hv[cc].w};
        bitonic256(s, lane);
        srt[cc][0] = s[0]; srt[cc][1] = s[1]; srt[cc][2] = s[2]; srt[cc][3] = s[3];
    }
#pragma unroll
    for (int r = 0; r < 4; ++r) {
        int e = 4 * lane + r;
        int slot = (e >> 6) * 65 + (e & 63);
        float4 vvv = make_float4(srt[0][r], srt[1][r], srt[2][r], srt[3][r]);
        *(float4*)&sm[wbase + slot * 4] = vvv;
    }

    float4 acc[4];
#pragma unroll
    for (int cc = 0; cc < 4; ++cc) acc[cc] = make_float4(0.f, 0.f, 0.f, 0.f);
#pragma unroll 4
    for (int i = 0; i < 64; ++i) {
        float4 w4 = *(const float4*)&wt1T[i * 256 + 4 * lane];
        float4 cv = *(const float4*)&sm[wbase + (go * 65 + i) * 4];
#pragma unroll
        for (int cc = 0; cc < 4; ++cc) {
            float cvv = (&cv.x)[cc];
            acc[cc].x += w4.x * cvv;
            acc[cc].y += w4.y * cvv;
            acc[cc].z += w4.z * cvv;
            acc[cc].w += w4.w * cvv;
        }
    }
#pragma unroll
    for (int r = 0; r < 4; ++r) {
        float bb = (&ba1v.x)[r];
        float4 vvv = make_float4((&acc[0].x)[r] + bb, (&acc[1].x)[r] + bb,
                                 (&acc[2].x)[r] + bb, (&acc[3].x)[r] + bb);
        *(float4*)&sm[wbase + (5 * lane + r) * 4] = vvv;
    }

    float4 acc2[4];
#pragma unroll
    for (int cc = 0; cc < 4; ++cc) acc2[cc] = make_float4(0.f, 0.f, 0.f, 0.f);
#pragma unroll 4
    for (int i = 0; i < 32; ++i) {
        float4 w4 = *(const float4*)&wt2T[i * 256 + 4 * lane];
        int idx = ((i & 7) << 5) + (go << 2) + (i >> 3);
        int slotA = idx + (idx >> 2);
        float4 av = *(const float4*)&sm[wbase + slotA * 4];
#pragma unroll
        for (int cc = 0; cc < 4; ++cc) {
            float avv = (&av.x)[cc];
            acc2[cc].x += w4.x * avv;
            acc2[cc].y += w4.y * avv;
            acc2[cc].z += w4.z * avv;
            acc2[cc].w += w4.w * avv;
        }
    }
#pragma unroll
    for (int cc = 0; cc < 4; ++cc) {
        float zx = acc2[cc].x + ba2v.x;
        float zy = acc2[cc].y + ba2v.y;
        float zz = acc2[cc].z + ba2v.z;
        float zw = acc2[cc].w + ba2v.w;
        float4 res;
        res.x = hv[cc].x * (1.f / (1.f + __expf(-zx)));
        res.y = hv[cc].y * (1.f / (1.f + __expf(-zy)));
        res.z = hv[cc].z * (1.f / (1.f + __expf(-zz)));
        res.w = hv[cc].w * (1.f / (1.f + __expf(-zw)));
        *(float4*)(t2 + (size_t)(colBase + cc) * CCH + 4 * lane) = res;
    }
}

// ---------- K4: grouped conv k=5 over t2 [B,L2,C] -> out [B,C,L3] ----------
// 16 output positions per block; acc[16]; 5 weight float4s live.
__global__ __launch_bounds__(256, 6) void conv3_kernel(const float* __restrict__ hm,
                                                       const float* __restrict__ w3,
                                                       const float* __restrict__ b3,
                                                       float* __restrict__ out) {
    __shared__ float ts[5280];   // [20][264]
    const int b = blockIdx.y;
    const int l0 = blockIdx.x * 16;
    const int t = threadIdx.x;

#pragma unroll
    for (int j = 0; j < 5; ++j) {
        int f = t + 256 * j;            // 1280 granules = 20 rows * 64
        int p = f >> 6;
        int c4 = (f & 63) * 4;
        int row = min(l0 + p, L2V - 1);
        float4 v = *(const float4*)(hm + (size_t)(b * L2V + row) * CCH + c4);
        *(float4*)&ts[p * 264 + c4] = v;
    }
    __syncthreads();

    const int oc = t;
    const int go = t >> 5;
    float acc[16];
#pragma unroll
    for (int l = 0; l < 16; ++l) acc[l] = 0.f;

    {
        const float4* w3r = (const float4*)(w3 + oc * 160);
#pragma unroll 1
        for (int i4 = 0; i4 < 8; ++i4) {
            float4 wa = w3r[5 * i4 + 0];
            float4 wb = w3r[5 * i4 + 1];
            float4 wc = w3r[5 * i4 + 2];
            float4 wd = w3r[5 * i4 + 3];
            float4 we = w3r[5 * i4 + 4];
            const int colbase = go * 32 + i4 * 4;
#pragma unroll
            for (int p = 0; p < 20; ++p) {
                float4 rv = *(const float4*)&ts[p * 264 + colbase];
#pragma unroll
                for (int cc = 0; cc < 4; ++cc) {
                    float xv = F4C(rv, cc);
#pragma unroll
                    for (int k = 0; k < 5; ++k) {
                        const int l = p - k;
                        if (l >= 0 && l < 16) acc[l] += TAP20(wa, wb, wc, wd, we, cc * 5 + k) * xv;
                    }
                }
            }
        }
    }
    float bias = b3[oc];
    float* dst = out + (size_t)(b * CCH + oc) * L3V + l0;
#pragma unroll
    for (int l4 = 0; l4 < 4; ++l4) {
        int gl = l0 + 4 * l4;
        if (gl + 3 < L3V) {
            float4 v;
            v.x = acc[4 * l4 + 0] + bias;
            v.y = acc[4 * l4 + 1] + bias;
            v.z = acc[4 * l4 + 2] + bias;
            v.w = acc[4 * l4 + 3] + bias;
            *(float4*)(dst + 4 * l4) = v;
        } else {
#pragma unroll
            for (int c = 0; c < 4; ++c) {
                if (gl + c < L3V) dst[4 * l4 + c] = acc[4 * l4 + c] + bias;
            }
        }
    }
}

extern "C" void kernel_launch(void* const* d_in, const int* in_sizes, int n_in,
                              void* d_out, int out_size, void* d_ws, size_t ws_size,
                              hipStream_t stream) {
    const float* x   = (const float*)d_in[0];
    const float* w1  = (const float*)d_in[1];
    const float* b1  = (const float*)d_in[2];
    const float* w2  = (const float*)d_in[3];
    const float* b2  = (const float*)d_in[4];
    const float* wa1 = (const float*)d_in[5];
    const float* ba1 = (const float*)d_in[6];
    const float* wa2 = (const float*)d_in[7];
    const float* ba2 = (const float*)d_in[8];
    const float* w3  = (const float*)d_in[9];
    const float* b3  = (const float*)d_in[10];
    float* out = (float*)d_out;

    char* ws = (char*)d_ws;
    float* t2   = (float*)ws;                                   // 8*4092*256 f32 = 33.5 MB
    float* wt1T = (float*)(ws + ((size_t)48 << 20));            // 64*256 f32
    float* wt2T = wt1T + 64 * 256;                              // 32*256 f32

    hipLaunchKernelGGL(prep_kernel, dim3(96), dim3(256), 0, stream, wa1, wa2, wt1T, wt2T);
    hipLaunchKernelGGL(conv12_kernel, dim3(256, BB), dim3(256), 0, stream, x, w1, b1, w2, b2, t2);
    hipLaunchKernelGGL(attn_kernel, dim3(2046), dim3(256), 0, stream, t2, wt1T, wt2T, ba1, ba2);
    hipLaunchKernelGGL(conv3_kernel, dim3(256, BB), dim3(256), 0, stream, t2, w3, b3, out);
}

// Round 5
// 300.929 us; speedup vs baseline: 1.6721x; 1.6435x over previous
//
#include <hip/hip_runtime.h>
#include <math.h>

#define BB 8
#define CCH 256
#define LLEN 4096
#define L1V 4094
#define L2V 4092
#define L3V 4088
#define NCOL (BB * L2V)   // 32736

// ---- compile-time component / register selection (folds after unroll; no address-of) ----
#define F4C(v, j) ((j) == 0 ? (v).x : ((j) == 1 ? (v).y : ((j) == 2 ? (v).z : (v).w)))
// scalar from 5 float4s (20 consecutive floats)
#define SEL5(n, a0, a1, a2, a3, a4) \
    ((n) < 4 ? F4C(a0, (n)) : (n) < 8 ? F4C(a1, (n) - 4) : (n) < 12 ? F4C(a2, (n) - 8) : \
     (n) < 16 ? F4C(a3, (n) - 12) : F4C(a4, (n) - 16))
// float4 from 6 / 8 named regs
#define SEL6R(n, r0, r1, r2, r3, r4, r5) \
    ((n) == 0 ? (r0) : (n) == 1 ? (r1) : (n) == 2 ? (r2) : (n) == 3 ? (r3) : (n) == 4 ? (r4) : (r5))
#define SEL8R(n, r0, r1, r2, r3, r4, r5, r6, r7) \
    ((n) == 0 ? (r0) : (n) == 1 ? (r1) : (n) == 2 ? (r2) : (n) == 3 ? (r3) : \
     (n) == 4 ? (r4) : (n) == 5 ? (r5) : (n) == 6 ? (r6) : (r7))
// weight taps: scalar f of 12 / 20 packed floats
#define TAP12(a, b, c, f) ((f) < 4 ? F4C(a, (f)) : ((f) < 8 ? F4C(b, (f) - 4) : F4C(c, (f) - 8)))
#define TAP20(a, b, c, d, e, f) \
    ((f) < 4 ? F4C(a, (f)) : ((f) < 8 ? F4C(b, (f) - 4) : ((f) < 12 ? F4C(c, (f) - 8) : \
     ((f) < 16 ? F4C(d, (f) - 12) : F4C(e, (f) - 16)))))

// ---------- prep: transpose attention weights into ws ----------
__global__ void prep_kernel(const float* __restrict__ wa1, const float* __restrict__ wa2,
                            float* __restrict__ wt1T, float* __restrict__ wt2T) {
    int i = blockIdx.x;
    int o = threadIdx.x;
    if (i < 64) {
        wt1T[i * 256 + o] = wa1[o * 64 + i];
    } else {
        int ii = i - 64;
        if (ii < 32) wt2T[ii * 256 + o] = wa2[o * 32 + ii];
    }
}

// ---------- K1: fused conv1(k=3)+shuffle+conv2(k=3)+shuffle : x -> t2 [B,L2,C] ----------
// 16 output positions / block. All accumulator indices literal; guard-free loops.
__global__ __launch_bounds__(256, 4) void conv12_kernel(const float* __restrict__ x,
                                                        const float* __restrict__ w1,
                                                        const float* __restrict__ b1,
                                                        const float* __restrict__ w2,
                                                        const float* __restrict__ b2,
                                                        float* __restrict__ t2) {
    // buffer lives: (a) x tile [256ch][20pos] contiguous; (b) h1 [18pos][260]; (c) out [16pos][260]
    __shared__ float xs[5120];
    const int b = blockIdx.y;
    const int l0 = blockIdx.x * 16;
    const int t = threadIdx.x;

    // ---- stage x tile (1280 float4 granules, LDS addr = 16B * f: conflict-free) ----
#pragma unroll
    for (int j = 0; j < 5; ++j) {
        int f = t + 256 * j;            // 0..1279
        int row = f / 5;
        int q = f - row * 5;
        size_t rb = (size_t)(b * CCH + row) * LLEN;
        int base = l0 + 4 * q;
        float4 v;
        if (base + 3 < LLEN) {
            v = *(const float4*)(x + rb + base);
        } else {
            v.x = x[rb + min(base + 0, LLEN - 1)];
            v.y = x[rb + min(base + 1, LLEN - 1)];
            v.z = x[rb + min(base + 2, LLEN - 1)];
            v.w = x[rb + min(base + 3, LLEN - 1)];
        }
        *(float4*)&xs[4 * f] = v;
    }
    __syncthreads();

    const int oc = t;
    const int go = oc >> 5;
    const int nc = (oc & 31) * 8 + go;   // channel-shuffle scatter

    // ---- conv1: 18 h1 positions; acc index = literal unrolled l ----
    float acc1[18];
#pragma unroll
    for (int l = 0; l < 18; ++l) acc1[l] = 0.f;
    {
        const float4* w1r = (const float4*)(w1 + oc * 96);
#pragma unroll 1
        for (int c4 = 0; c4 < 8; ++c4) {
            float4 wa = w1r[3 * c4 + 0];
            float4 wb = w1r[3 * c4 + 1];
            float4 wc = w1r[3 * c4 + 2];
#pragma unroll
            for (int ii = 0; ii < 4; ++ii) {
                const float* xrow = &xs[(go * 32 + c4 * 4 + ii) * 20];
                float4 v0 = *(const float4*)(xrow + 0);
                float4 v1 = *(const float4*)(xrow + 4);
                float4 v2 = *(const float4*)(xrow + 8);
                float4 v3 = *(const float4*)(xrow + 12);
                float4 v4 = *(const float4*)(xrow + 16);
                float w0 = TAP12(wa, wb, wc, ii * 3 + 0);
                float w1v = TAP12(wa, wb, wc, ii * 3 + 1);
                float w2v = TAP12(wa, wb, wc, ii * 3 + 2);
#pragma unroll
                for (int l = 0; l < 18; ++l) {
                    acc1[l] += w0 * SEL5(l + 0, v0, v1, v2, v3, v4)
                             + w1v * SEL5(l + 1, v0, v1, v2, v3, v4)
                             + w2v * SEL5(l + 2, v0, v1, v2, v3, v4);
                }
            }
        }
    }
    float bias1 = b1[oc];
    __syncthreads();

    // ---- stage h1 (shuffled channels), pitch 260 ----
#pragma unroll
    for (int l = 0; l < 18; ++l) xs[l * 260 + nc] = acc1[l] + bias1;
    __syncthreads();

    // ---- conv2: 16 outputs; chunked rows in named regs, literal acc indices ----
    float acc2[16];
#pragma unroll
    for (int l = 0; l < 16; ++l) acc2[l] = 0.f;
    {
        const float4* w2r = (const float4*)(w2 + oc * 96);
#pragma unroll 1
        for (int i4 = 0; i4 < 8; ++i4) {
            float4 wa = w2r[3 * i4 + 0];
            float4 wb = w2r[3 * i4 + 1];
            float4 wc = w2r[3 * i4 + 2];
            const int colbase = go * 32 + i4 * 4;
#pragma unroll
            for (int lq = 0; lq < 4; ++lq) {
                float4 r0 = *(const float4*)&xs[(4 * lq + 0) * 260 + colbase];
                float4 r1 = *(const float4*)&xs[(4 * lq + 1) * 260 + colbase];
                float4 r2 = *(const float4*)&xs[(4 * lq + 2) * 260 + colbase];
                float4 r3 = *(const float4*)&xs[(4 * lq + 3) * 260 + colbase];
                float4 r4 = *(const float4*)&xs[(4 * lq + 4) * 260 + colbase];
                float4 r5 = *(const float4*)&xs[(4 * lq + 5) * 260 + colbase];
#pragma unroll
                for (int lp = 0; lp < 4; ++lp) {
#pragma unroll
                    for (int cc = 0; cc < 4; ++cc) {
                        acc2[4 * lq + lp] +=
                            TAP12(wa, wb, wc, cc * 3 + 0) * F4C(SEL6R(lp + 0, r0, r1, r2, r3, r4, r5), cc)
                          + TAP12(wa, wb, wc, cc * 3 + 1) * F4C(SEL6R(lp + 1, r0, r1, r2, r3, r4, r5), cc)
                          + TAP12(wa, wb, wc, cc * 3 + 2) * F4C(SEL6R(lp + 2, r0, r1, r2, r3, r4, r5), cc);
                    }
                }
            }
        }
    }
    float bias2 = b2[oc];
    __syncthreads();

    // ---- stage conv2 output (shuffled channels) ----
#pragma unroll
    for (int l = 0; l < 16; ++l) xs[l * 260 + nc] = acc2[l] + bias2;
    __syncthreads();

    // ---- coalesced float4 store to t2 ----
#pragma unroll
    for (int j = 0; j < 4; ++j) {
        int idx = t + 256 * j;          // 1024 granules = 16 rows * 64
        int row = idx >> 6;
        int c4 = (idx & 63) * 4;
        if (l0 + row < L2V) {
            float4 v = *(const float4*)&xs[row * 260 + c4];
            *(float4*)(t2 + (size_t)(b * L2V + l0 + row) * CCH + c4) = v;
        }
    }
}

// ---------- K3: per-column sort + attention gate, in-place on t2 (unchanged) ----------
__device__ __forceinline__ void ce_pair(float& a, float& b, bool up) {
    float lo = fminf(a, b), hi = fmaxf(a, b);
    a = up ? lo : hi;
    b = up ? hi : lo;
}

__device__ __forceinline__ void bitonic256(float v[4], int lane) {
#pragma unroll
    for (int k = 2; k <= 256; k <<= 1) {
#pragma unroll
        for (int j = k >> 1; j > 0; j >>= 1) {
            if (j >= 4) {
                int lm = j >> 2;
                bool upper = (lane & lm) != 0;
#pragma unroll
                for (int r = 0; r < 4; ++r) {
                    float other = __shfl_xor(v[r], lm, 64);
                    bool dirUp = (((4 * lane + r) & k) == 0);
                    bool keepMin = (dirUp != upper);
                    float lo = fminf(v[r], other), hi = fmaxf(v[r], other);
                    v[r] = keepMin ? lo : hi;
                }
            } else if (j == 2) {
#pragma unroll
                for (int r = 0; r < 2; ++r) {
                    bool up = (((4 * lane + r) & k) == 0);
                    ce_pair(v[r], v[r + 2], up);
                }
            } else {
#pragma unroll
                for (int r = 0; r < 4; r += 2) {
                    bool up = (((4 * lane + r) & k) == 0);
                    ce_pair(v[r], v[r + 1], up);
                }
            }
        }
    }
}

__global__ __launch_bounds__(256, 4) void attn_kernel(float* __restrict__ t2,
                                                      const float* __restrict__ wt1T,
                                                      const float* __restrict__ wt2T,
                                                      const float* __restrict__ ba1,
                                                      const float* __restrict__ ba2) {
    __shared__ float sm[8320];           // 4 waves * 2080 floats
    const int t = threadIdx.x;
    const int wv = t >> 6;
    const int lane = t & 63;
    const int wbase = wv * 2080;
    const int go = lane >> 3;

    float4 ba1v = *(const float4*)&ba1[4 * lane];
    float4 ba2v = *(const float4*)&ba2[4 * lane];

    const int colBase = blockIdx.x * 16 + wv * 4;

    float4 hv[4];
#pragma unroll
    for (int cc = 0; cc < 4; ++cc) {
        hv[cc] = *(const float4*)(t2 + (size_t)(colBase + cc) * CCH + 4 * lane);
    }
#pragma unroll
    for (int r = 0; r < 4; ++r) {
        int e = 4 * lane + r;
        int slot = ((e >> 6) + 4) * 65 + (e & 63);
        float4 vvv = make_float4(F4C(hv[0], r), F4C(hv[1], r), F4C(hv[2], r), F4C(hv[3], r));
        *(float4*)&sm[wbase + slot * 4] = vvv;
    }
    float srt[4][4];
#pragma unroll
    for (int cc = 0; cc < 4; ++cc) {
        float s[4] = {hv[cc].x, hv[cc].y, hv[cc].z, hv[cc].w};
        bitonic256(s, lane);
        srt[cc][0] = s[0]; srt[cc][1] = s[1]; srt[cc][2] = s[2]; srt[cc][3] = s[3];
    }
#pragma unroll
    for (int r = 0; r < 4; ++r) {
        int e = 4 * lane + r;
        int slot = (e >> 6) * 65 + (e & 63);
        float4 vvv = make_float4(srt[0][r], srt[1][r], srt[2][r], srt[3][r]);
        *(float4*)&sm[wbase + slot * 4] = vvv;
    }

    float4 acc[4];
#pragma unroll
    for (int cc = 0; cc < 4; ++cc) acc[cc] = make_float4(0.f, 0.f, 0.f, 0.f);
#pragma unroll 4
    for (int i = 0; i < 64; ++i) {
        float4 w4 = *(const float4*)&wt1T[i * 256 + 4 * lane];
        float4 cv = *(const float4*)&sm[wbase + (go * 65 + i) * 4];
#pragma unroll
        for (int cc = 0; cc < 4; ++cc) {
            float cvv = F4C(cv, cc);
            acc[cc].x += w4.x * cvv;
            acc[cc].y += w4.y * cvv;
            acc[cc].z += w4.z * cvv;
            acc[cc].w += w4.w * cvv;
        }
    }
#pragma unroll
    for (int r = 0; r < 4; ++r) {
        float bb = F4C(ba1v, r);
        float4 vvv = make_float4(F4C(acc[0], r) + bb, F4C(acc[1], r) + bb,
                                 F4C(acc[2], r) + bb, F4C(acc[3], r) + bb);
        *(float4*)&sm[wbase + (5 * lane + r) * 4] = vvv;
    }

    float4 acc2[4];
#pragma unroll
    for (int cc = 0; cc < 4; ++cc) acc2[cc] = make_float4(0.f, 0.f, 0.f, 0.f);
#pragma unroll 4
    for (int i = 0; i < 32; ++i) {
        float4 w4 = *(const float4*)&wt2T[i * 256 + 4 * lane];
        int idx = ((i & 7) << 5) + (go << 2) + (i >> 3);
        int slotA = idx + (idx >> 2);
        float4 av = *(const float4*)&sm[wbase + slotA * 4];
#pragma unroll
        for (int cc = 0; cc < 4; ++cc) {
            float avv = F4C(av, cc);
            acc2[cc].x += w4.x * avv;
            acc2[cc].y += w4.y * avv;
            acc2[cc].z += w4.z * avv;
            acc2[cc].w += w4.w * avv;
        }
    }
#pragma unroll
    for (int cc = 0; cc < 4; ++cc) {
        float zx = acc2[cc].x + ba2v.x;
        float zy = acc2[cc].y + ba2v.y;
        float zz = acc2[cc].z + ba2v.z;
        float zw = acc2[cc].w + ba2v.w;
        float4 res;
        res.x = hv[cc].x * (1.f / (1.f + __expf(-zx)));
        res.y = hv[cc].y * (1.f / (1.f + __expf(-zy)));
        res.z = hv[cc].z * (1.f / (1.f + __expf(-zz)));
        res.w = hv[cc].w * (1.f / (1.f + __expf(-zw)));
        *(float4*)(t2 + (size_t)(colBase + cc) * CCH + 4 * lane) = res;
    }
}

// ---------- K4: grouped conv k=5 over t2 [B,L2,C] -> out [B,C,L3] ----------
// 16 outputs/block; literal acc indices, guard-free.
__global__ __launch_bounds__(256, 4) void conv3_kernel(const float* __restrict__ hm,
                                                       const float* __restrict__ w3,
                                                       const float* __restrict__ b3,
                                                       float* __restrict__ out) {
    __shared__ float ts[5280];   // [20][264]
    const int b = blockIdx.y;
    const int l0 = blockIdx.x * 16;
    const int t = threadIdx.x;

#pragma unroll
    for (int j = 0; j < 5; ++j) {
        int f = t + 256 * j;            // 1280 granules = 20 rows * 64
        int p = f >> 6;
        int c4 = (f & 63) * 4;
        int row = min(l0 + p, L2V - 1);
        float4 v = *(const float4*)(hm + (size_t)(b * L2V + row) * CCH + c4);
        *(float4*)&ts[p * 264 + c4] = v;
    }
    __syncthreads();

    const int oc = t;
    const int go = t >> 5;
    float acc[16];
#pragma unroll
    for (int l = 0; l < 16; ++l) acc[l] = 0.f;

    {
        const float4* w3r = (const float4*)(w3 + oc * 160);
#pragma unroll 1
        for (int i4 = 0; i4 < 8; ++i4) {
            float4 wa = w3r[5 * i4 + 0];
            float4 wb = w3r[5 * i4 + 1];
            float4 wc = w3r[5 * i4 + 2];
            float4 wd = w3r[5 * i4 + 3];
            float4 we = w3r[5 * i4 + 4];
            const int colbase = go * 32 + i4 * 4;
#pragma unroll
            for (int lq = 0; lq < 4; ++lq) {
                float4 r0 = *(const float4*)&ts[(4 * lq + 0) * 264 + colbase];
                float4 r1 = *(const float4*)&ts[(4 * lq + 1) * 264 + colbase];
                float4 r2 = *(const float4*)&ts[(4 * lq + 2) * 264 + colbase];
                float4 r3 = *(const float4*)&ts[(4 * lq + 3) * 264 + colbase];
                float4 r4 = *(const float4*)&ts[(4 * lq + 4) * 264 + colbase];
                float4 r5 = *(const float4*)&ts[(4 * lq + 5) * 264 + colbase];
                float4 r6 = *(const float4*)&ts[(4 * lq + 6) * 264 + colbase];
                float4 r7 = *(const float4*)&ts[(4 * lq + 7) * 264 + colbase];
#pragma unroll
                for (int lp = 0; lp < 4; ++lp) {
#pragma unroll
                    for (int cc = 0; cc < 4; ++cc) {
                        acc[4 * lq + lp] +=
                            TAP20(wa, wb, wc, wd, we, cc * 5 + 0) * F4C(SEL8R(lp + 0, r0, r1, r2, r3, r4, r5, r6, r7), cc)
                          + TAP20(wa, wb, wc, wd, we, cc * 5 + 1) * F4C(SEL8R(lp + 1, r0, r1, r2, r3, r4, r5, r6, r7), cc)
                          + TAP20(wa, wb, wc, wd, we, cc * 5 + 2) * F4C(SEL8R(lp + 2, r0, r1, r2, r3, r4, r5, r6, r7), cc)
                          + TAP20(wa, wb, wc, wd, we, cc * 5 + 3) * F4C(SEL8R(lp + 3, r0, r1, r2, r3, r4, r5, r6, r7), cc)
                          + TAP20(wa, wb, wc, wd, we, cc * 5 + 4) * F4C(SEL8R(lp + 4, r0, r1, r2, r3, r4, r5, r6, r7), cc);
                    }
                }
            }
        }
    }
    float bias = b3[oc];
    float* dst = out + (size_t)(b * CCH + oc) * L3V + l0;
#pragma unroll
    for (int l4 = 0; l4 < 4; ++l4) {
        int gl = l0 + 4 * l4;
        if (gl + 3 < L3V) {
            float4 v;
            v.x = acc[4 * l4 + 0] + bias;
            v.y = acc[4 * l4 + 1] + bias;
            v.z = acc[4 * l4 + 2] + bias;
            v.w = acc[4 * l4 + 3] + bias;
            *(float4*)(dst + 4 * l4) = v;
        } else {
#pragma unroll
            for (int c = 0; c < 4; ++c) {
                if (gl + c < L3V) dst[4 * l4 + c] = acc[4 * l4 + c] + bias;
            }
        }
    }
}

extern "C" void kernel_launch(void* const* d_in, const int* in_sizes, int n_in,
                              void* d_out, int out_size, void* d_ws, size_t ws_size,
                              hipStream_t stream) {
    const float* x   = (const float*)d_in[0];
    const float* w1  = (const float*)d_in[1];
    const float* b1  = (const float*)d_in[2];
    const float* w2  = (const float*)d_in[3];
    const float* b2  = (const float*)d_in[4];
    const float* wa1 = (const float*)d_in[5];
    const float* ba1 = (const float*)d_in[6];
    const float* wa2 = (const float*)d_in[7];
    const float* ba2 = (const float*)d_in[8];
    const float* w3  = (const float*)d_in[9];
    const float* b3  = (const float*)d_in[10];
    float* out = (float*)d_out;

    char* ws = (char*)d_ws;
    float* t2   = (float*)ws;                                   // 8*4092*256 f32 = 33.5 MB
    float* wt1T = (float*)(ws + ((size_t)48 << 20));            // 64*256 f32
    float* wt2T = wt1T + 64 * 256;                              // 32*256 f32

    hipLaunchKernelGGL(prep_kernel, dim3(96), dim3(256), 0, stream, wa1, wa2, wt1T, wt2T);
    hipLaunchKernelGGL(conv12_kernel, dim3(256, BB), dim3(256), 0, stream, x, w1, b1, w2, b2, t2);
    hipLaunchKernelGGL(attn_kernel, dim3(2046), dim3(256), 0, stream, t2, wt1T, wt2T, ba1, ba2);
    hipLaunchKernelGGL(conv3_kernel, dim3(256, BB), dim3(256), 0, stream, t2, w3, b3, out);
}